// Round 1
// baseline (639.245 us; speedup 1.0000x reference)
//
#include <hip/hip_runtime.h>
#include <stdint.h>

// VenomSpmm: y = x @ (W*mask)^T + bias, mask keeps k%8 in {0,2} (2:8 structured).
// Phase 1: compact+convert fp32 -> bf16 into d_ws (unchanged from prior round).
// Phase 2: 256x256x64 8-phase pipelined bf16 MFMA GEMM (T1+T2+T3+T4+T5):
//   - 8 waves (2M x 4N), per-wave 128x64 output, 16x16x32 MFMA
//   - 128 KiB LDS: 2 buffers x (A 256x64 + B 256x64) bf16, stored as 2 halves
//   - global_load_lds staging with pre-swizzled SOURCE (cb ^= (row&4)<<3),
//     ds_read applies the same XOR -> involution (both-sides swizzle, rule 21)
//   - counted s_waitcnt vmcnt(4) only at phases 4/8; raw s_barrier; setprio
//     around MFMA clusters; bijective XCD-chunked blockIdx swizzle.

typedef __attribute__((ext_vector_type(8))) short short8;   // 8 bf16 = 4 VGPRs
typedef __attribute__((ext_vector_type(4))) float float4_t; // 4 fp32 acc

typedef unsigned short u16;
typedef unsigned int   u32;

#define M_TOT 16384
#define N_TOT 4096
#define K_ACT 4096
#define K_C   1024
#define NT    16      // K-tiles of 64 along compacted K

typedef __attribute__((address_space(1))) void GlobVoid;
typedef __attribute__((address_space(3))) void LdsVoid;

static __device__ __forceinline__ u32 f32_to_bf16_rne(float f) {
    u32 u = __float_as_uint(f);
    u32 rounded = u + 0x7FFFu + ((u >> 16) & 1u);
    return rounded >> 16;
}

// ---- compaction: one 8-fp32 group (32B) -> 2 bf16 (4B); need only first 16B ----
__global__ __launch_bounds__(256) void compact_k(const float4* __restrict__ src,
                                                 u32* __restrict__ dst, int n) {
    int i = blockIdx.x * 256 + threadIdx.x;
    if (i >= n) return;
    float4 g = src[(size_t)i * 2];  // first 16B of the 32B group: e0,e1,e2,e3
    dst[i] = f32_to_bf16_rne(g.x) | (f32_to_bf16_rne(g.z) << 16);
}

// Stage one 128x64 bf16 half-tile (16 KB) into LDS, linear dest, source
// pre-swizzled so that LDS[row][cb] holds global[row][cb ^ ((row&4)<<3)].
// 512 threads x 2 loads x 16B. lds_half is wave-uniform base region.
static __device__ __forceinline__ void stage_half(const u16* __restrict__ src,
                                                  int row0, int kt,
                                                  u16* lds_half,
                                                  int wave, int lane) {
#pragma unroll
    for (int c = 0; c < 2; ++c) {
        const int blk = c * 8 + wave;            // 0..15 (1KB chunks)
        const int r   = blk * 8 + (lane >> 3);   // row 0..127
        const int cb  = (lane & 7) * 16;         // byte col 0..112
        const int cbs = cb ^ ((r & 4) << 3);     // swizzled source col
        const u16* g = src + (size_t)(row0 + r) * K_C + kt * 64 + (cbs >> 1);
        __builtin_amdgcn_global_load_lds((GlobVoid*)g,
                                         (LdsVoid*)(lds_half + blk * 512),
                                         16, 0, 0);
    }
}

// LDS layout (u16 units): buf*32768 + (A=0/B=16384) + half*8192
//   buf0: A.h0=0      A.h1=8192   B.h0=16384  B.h1=24576
//   buf1: A.h0=32768  A.h1=40960  B.h0=49152  B.h1=57344

#define PHASE(ABASE, BBASE, MH, NH, STAGE_STMT, VMCNT_STMT)                     \
    do {                                                                        \
        short8 afr[4][2], bfr[2][2];                                            \
        const u16* Ah = lds + (ABASE);                                          \
        const u16* Bh = lds + (BBASE);                                          \
        _Pragma("unroll")                                                       \
        for (int i = 0; i < 4; ++i) {                                           \
            afr[i][0] = *(const short8*)(Ah + arow + i * 1024 + ck0);           \
            afr[i][1] = *(const short8*)(Ah + arow + i * 1024 + ck1);           \
        }                                                                       \
        _Pragma("unroll")                                                       \
        for (int j = 0; j < 2; ++j) {                                           \
            bfr[j][0] = *(const short8*)(Bh + brow + j * 1024 + ck0);           \
            bfr[j][1] = *(const short8*)(Bh + brow + j * 1024 + ck1);           \
        }                                                                       \
        STAGE_STMT;                                                             \
        __builtin_amdgcn_s_barrier();                                           \
        asm volatile("s_waitcnt lgkmcnt(0)" ::: "memory");                      \
        __builtin_amdgcn_sched_barrier(0);                                      \
        __builtin_amdgcn_s_setprio(1);                                          \
        _Pragma("unroll")                                                       \
        for (int i = 0; i < 4; ++i) {                                           \
            _Pragma("unroll")                                                   \
            for (int j = 0; j < 2; ++j) {                                       \
                acc[MH][NH][i][j] = __builtin_amdgcn_mfma_f32_16x16x32_bf16(    \
                    afr[i][0], bfr[j][0], acc[MH][NH][i][j], 0, 0, 0);          \
                acc[MH][NH][i][j] = __builtin_amdgcn_mfma_f32_16x16x32_bf16(    \
                    afr[i][1], bfr[j][1], acc[MH][NH][i][j], 0, 0, 0);          \
            }                                                                   \
        }                                                                       \
        __builtin_amdgcn_s_setprio(0);                                          \
        VMCNT_STMT;                                                             \
        __builtin_amdgcn_s_barrier();                                           \
    } while (0)

__global__ __launch_bounds__(512, 2) void gemm_bt(const u16* __restrict__ A,
                                                  const u16* __restrict__ B,
                                                  const float* __restrict__ bias,
                                                  float* __restrict__ C) {
    __shared__ u16 lds[65536];  // 128 KiB

    const int tid  = threadIdx.x;
    const int lane = tid & 63;
    const int wave = tid >> 6;     // 0..7
    const int wm   = wave >> 2;    // 0..1 (M)
    const int wn   = wave & 3;     // 0..3 (N)
    const int fr   = lane & 15;    // fragment row index
    const int q    = lane >> 4;    // k-quad (8 bf16 = 16B)

    // Bijective XCD-chunked swizzle: 1024 wgs, 8 XCDs, 128 per chunk.
    // Chunk = 8 consecutive m-panels x all 16 n-panels -> A locality in L2.
    const int wg  = blockIdx.x;
    const int swz = (wg & 7) * 128 + (wg >> 3);
    const int m0  = (swz >> 4) * 256;
    const int n0  = (swz & 15) * 256;

    // Per-thread LDS read offsets (u16 units). cb = ks*64 + q*16 bytes,
    // swizzled by ((row&4)<<3); row&4 == fr&4 for all fragment rows.
    const int ck0 = (((0 * 64) + q * 16) ^ ((fr & 4) << 3)) >> 1;
    const int ck1 = (((1 * 64) + q * 16) ^ ((fr & 4) << 3)) >> 1;
    const int arow = (wm * 64 + fr) * 64;  // + i*1024 + half*8192
    const int brow = (wn * 32 + fr) * 64;  // + j*1024 + half*8192

    float4_t acc[2][2][4][2];
    const float4_t fzero = {0.f, 0.f, 0.f, 0.f};
#pragma unroll
    for (int mh = 0; mh < 2; ++mh)
#pragma unroll
        for (int nh = 0; nh < 2; ++nh)
#pragma unroll
            for (int i = 0; i < 4; ++i)
#pragma unroll
                for (int j = 0; j < 2; ++j) acc[mh][nh][i][j] = fzero;

    // ---- prologue: tile0 fully into buf0, tile1 halves h0 into buf1 ----
    stage_half(A, m0 + 0,   0, lds + 0,     wave, lane);  // A0(0)
    stage_half(B, n0 + 0,   0, lds + 16384, wave, lane);  // B0(0)
    stage_half(A, m0 + 128, 0, lds + 8192,  wave, lane);  // A1(0)
    stage_half(B, n0 + 128, 0, lds + 24576, wave, lane);  // B1(0)
    stage_half(A, m0 + 0,   1, lds + 32768, wave, lane);  // A0(1) in flight
    stage_half(B, n0 + 0,   1, lds + 49152, wave, lane);  // B0(1) in flight
    asm volatile("s_waitcnt vmcnt(4)" ::: "memory");      // tile0 landed
    __builtin_amdgcn_s_barrier();

    // ---- main loop: 8 iterations, 2 K-tiles each ----
    for (int it = 0; it < NT / 2; ++it) {
        const int u  = 2 * it;
        const int t1 = u + 1;
        const int t2 = (u + 2 < NT) ? u + 2 : NT - 1;  // tail clamp (unread)
        const int t3 = (u + 3 < NT) ? u + 3 : NT - 1;

        // P1: buf0 (mh0,nh0) | stage A1(t1) -> buf1.A.h1
        PHASE(0, 16384, 0, 0,
              stage_half(A, m0 + 128, t1, lds + 40960, wave, lane), ((void)0));
        // P2: buf0 (mh0,nh1) | stage B1(t1) -> buf1.B.h1
        PHASE(0, 24576, 0, 1,
              stage_half(B, n0 + 128, t1, lds + 57344, wave, lane), ((void)0));
        // P3: buf0 (mh1,nh0) | stage A0(t2) -> buf0.A.h0
        PHASE(8192, 16384, 1, 0,
              stage_half(A, m0 + 0, t2, lds + 0, wave, lane), ((void)0));
        // P4: buf0 (mh1,nh1) | stage B0(t2) -> buf0.B.h0 | vmcnt(4): tile t1 landed
        PHASE(8192, 24576, 1, 1,
              stage_half(B, n0 + 0, t2, lds + 16384, wave, lane),
              asm volatile("s_waitcnt vmcnt(4)" ::: "memory"));
        // P5: buf1 (mh0,nh0) | stage A1(t2) -> buf0.A.h1
        PHASE(32768, 49152, 0, 0,
              stage_half(A, m0 + 128, t2, lds + 8192, wave, lane), ((void)0));
        // P6: buf1 (mh0,nh1) | stage B1(t2) -> buf0.B.h1
        PHASE(32768, 57344, 0, 1,
              stage_half(B, n0 + 128, t2, lds + 24576, wave, lane), ((void)0));
        // P7: buf1 (mh1,nh0) | stage A0(t3) -> buf1.A.h0
        PHASE(40960, 49152, 1, 0,
              stage_half(A, m0 + 0, t3, lds + 32768, wave, lane), ((void)0));
        // P8: buf1 (mh1,nh1) | stage B0(t3) -> buf1.B.h0 | vmcnt(4): tile t2 landed
        PHASE(40960, 57344, 1, 1,
              stage_half(B, n0 + 0, t3, lds + 49152, wave, lane),
              asm volatile("s_waitcnt vmcnt(4)" ::: "memory"));
    }

    // ---- epilogue: D mapping col = lane&15, row = (lane>>4)*4 + reg ----
    const int rq = (lane >> 4) * 4;
#pragma unroll
    for (int nh = 0; nh < 2; ++nh) {
#pragma unroll
        for (int j = 0; j < 2; ++j) {
            const int col  = n0 + nh * 128 + wn * 32 + j * 16 + fr;
            const float bj = bias[col];
#pragma unroll
            for (int mh = 0; mh < 2; ++mh) {
#pragma unroll
                for (int i = 0; i < 4; ++i) {
                    const int row = m0 + mh * 128 + wm * 64 + i * 16 + rq;
#pragma unroll
                    for (int r = 0; r < 4; ++r) {
                        C[(size_t)(row + r) * N_TOT + col] = acc[mh][nh][i][j][r] + bj;
                    }
                }
            }
        }
    }
}

// ---- fallback (only if ws too small): slow but correct, pure fp32 ----
__global__ __launch_bounds__(256) void fallback_k(const float* __restrict__ X,
                                                  const float* __restrict__ W,
                                                  const float* __restrict__ bias,
                                                  float* __restrict__ out) {
    size_t idx = (size_t)blockIdx.x * 256 + threadIdx.x;
    int n    = (int)(idx & (N_TOT - 1));
    size_t m = idx >> 12;
    const float* xr = X + m * K_ACT;
    const float* wr = W + (size_t)n * K_ACT;
    float acc = 0.f;
    for (int g = 0; g < K_ACT / 8; ++g) {
        acc += xr[g * 8] * wr[g * 8] + xr[g * 8 + 2] * wr[g * 8 + 2];
    }
    out[idx] = acc + bias[n];
}

extern "C" void kernel_launch(void* const* d_in, const int* in_sizes, int n_in,
                              void* d_out, int out_size, void* d_ws, size_t ws_size,
                              hipStream_t stream) {
    const float* x    = (const float*)d_in[0];   // [16384, 4096] fp32
    const float* w    = (const float*)d_in[1];   // [4096, 4096] fp32
    const float* bias = (const float*)d_in[2];   // [4096] fp32
    float* out = (float*)d_out;                  // [16384, 4096] fp32

    const size_t xc_elems = (size_t)M_TOT * K_C;             // 16M u16 = 33.5 MB
    const size_t wc_elems = (size_t)N_TOT * K_C;             //  4M u16 =  8.4 MB
    const size_t need = (xc_elems + wc_elems) * sizeof(u16);

    if (ws_size >= need) {
        u16* xc = (u16*)d_ws;
        u16* wc = xc + xc_elems;

        const int ngx = M_TOT * (K_ACT / 8);                 // 8,388,608 groups
        const int ngw = N_TOT * (K_ACT / 8);                 // 2,097,152 groups
        compact_k<<<ngx / 256, 256, 0, stream>>>((const float4*)x, (u32*)xc, ngx);
        compact_k<<<ngw / 256, 256, 0, stream>>>((const float4*)w, (u32*)wc, ngw);

        gemm_bt<<<dim3(1024), dim3(512), 0, stream>>>(xc, wc, bias, out);
    } else {
        const size_t total = (size_t)M_TOT * N_TOT;
        fallback_k<<<(int)(total / 256), 256, 0, stream>>>(x, w, bias, out);
    }
}

// Round 2
// 612.427 us; speedup vs baseline: 1.0438x; 1.0438x over previous
//
#include <hip/hip_runtime.h>
#include <stdint.h>

// VenomSpmm: y = x @ (W*mask)^T + bias, mask keeps k%8 in {0,2} (2:8 structured).
// Phase 1: compact+convert fp32 -> bf16 into d_ws (unchanged).
// Phase 2: 256x256x64 8-phase pipelined bf16 MFMA GEMM.
//   Round-2 changes (LDS-read-bound fix):
//   - 2-bit XOR swizzle: col_byte ^= (row&3)<<5 on BOTH stage-source and
//     ds_read (involution). Flat [128][64bf16] rows have zero intrinsic bank
//     spread (128B stride); this spreads the 16 fragment rows + 4 k-quads
//     over all 8 bank-quads (8 lanes/quad = b128 optimum).
//   - Zigzag quadrant order (0,0)->(1,0)->(1,1)->(0,1) with fragment reuse:
//     32 ds_read_b128 per wave per K-tile instead of 48 (min is 24; the
//     extra 8 = A.h0 re-read keeps live-set at 48 VGPR to protect occupancy).
//   - Staging slots re-derived: region staged only after last reader phase,
//     lands under vmcnt(4) at P4/P8 (per-region proof in loop comments).

typedef __attribute__((ext_vector_type(8))) short short8;   // 8 bf16 = 4 VGPRs
typedef __attribute__((ext_vector_type(4))) float float4_t; // 4 fp32 acc

typedef unsigned short u16;
typedef unsigned int   u32;

#define M_TOT 16384
#define N_TOT 4096
#define K_ACT 4096
#define K_C   1024
#define NT    16      // K-tiles of 64 along compacted K

typedef __attribute__((address_space(1))) void GlobVoid;
typedef __attribute__((address_space(3))) void LdsVoid;

static __device__ __forceinline__ u32 f32_to_bf16_rne(float f) {
    u32 u = __float_as_uint(f);
    u32 rounded = u + 0x7FFFu + ((u >> 16) & 1u);
    return rounded >> 16;
}

// ---- compaction: one 8-fp32 group (32B) -> 2 bf16 (4B); need only first 16B ----
__global__ __launch_bounds__(256) void compact_k(const float4* __restrict__ src,
                                                 u32* __restrict__ dst, int n) {
    int i = blockIdx.x * 256 + threadIdx.x;
    if (i >= n) return;
    float4 g = src[(size_t)i * 2];  // first 16B of the 32B group: e0,e1,e2,e3
    dst[i] = f32_to_bf16_rne(g.x) | (f32_to_bf16_rne(g.z) << 16);
}

// Stage one 128x64 bf16 half-tile (16 KB) into LDS, linear dest.
// Source col pre-swizzled by ((row&3)<<5) bytes so that
// LDS[r][c] = global[r][c ^ ((r&3)<<5)]; reads apply the same XOR.
// Per-row the 8 swizzled 16B chunks permute within one 128B segment ->
// still fully coalesced. 512 threads x 2 loads x 16B.
static __device__ __forceinline__ void stage_half(const u16* __restrict__ src,
                                                  int row0, int kt,
                                                  u16* lds_half,
                                                  int wave, int lane) {
#pragma unroll
    for (int c = 0; c < 2; ++c) {
        const int blk = c * 8 + wave;            // 0..15 (1KB chunks)
        const int r   = blk * 8 + (lane >> 3);   // row 0..127
        const int cb  = (lane & 7) * 16;         // byte col 0..112
        const int cbs = cb ^ ((r & 3) << 5);     // 2-bit swizzled source col
        const u16* g = src + (size_t)(row0 + r) * K_C + kt * 64 + (cbs >> 1);
        __builtin_amdgcn_global_load_lds((GlobVoid*)g,
                                         (LdsVoid*)(lds_half + blk * 512),
                                         16, 0, 0);
    }
}

// LDS layout (u16 units): buf*32768 + (A=0/B=16384) + half*8192
//   buf0: A.h0=0      A.h1=8192   B.h0=16384  B.h1=24576
//   buf1: A.h0=32768  A.h1=40960  B.h0=49152  B.h1=57344

#define LOAD_AFR(HBASE)                                                         \
    do {                                                                        \
        _Pragma("unroll")                                                       \
        for (int i = 0; i < 4; ++i) {                                           \
            afr[i][0] = *(const short8*)(lds + (HBASE) + arow + i * 1024 + ck0);\
            afr[i][1] = *(const short8*)(lds + (HBASE) + arow + i * 1024 + ck1);\
        }                                                                       \
    } while (0)

#define LOAD_BFR(HBASE, BF)                                                     \
    do {                                                                        \
        _Pragma("unroll")                                                       \
        for (int j = 0; j < 2; ++j) {                                           \
            BF[j][0] = *(const short8*)(lds + (HBASE) + brow + j * 1024 + ck0); \
            BF[j][1] = *(const short8*)(lds + (HBASE) + brow + j * 1024 + ck1); \
        }                                                                       \
    } while (0)

#define MFMA16(MH, NH, BF)                                                      \
    do {                                                                        \
        __builtin_amdgcn_s_barrier();                                           \
        asm volatile("s_waitcnt lgkmcnt(0)" ::: "memory");                      \
        __builtin_amdgcn_sched_barrier(0);                                      \
        __builtin_amdgcn_s_setprio(1);                                          \
        _Pragma("unroll")                                                       \
        for (int i = 0; i < 4; ++i) {                                           \
            _Pragma("unroll")                                                   \
            for (int j = 0; j < 2; ++j) {                                       \
                acc[MH][NH][i][j] = __builtin_amdgcn_mfma_f32_16x16x32_bf16(    \
                    afr[i][0], BF[j][0], acc[MH][NH][i][j], 0, 0, 0);           \
                acc[MH][NH][i][j] = __builtin_amdgcn_mfma_f32_16x16x32_bf16(    \
                    afr[i][1], BF[j][1], acc[MH][NH][i][j], 0, 0, 0);           \
            }                                                                   \
        }                                                                       \
        __builtin_amdgcn_s_setprio(0);                                          \
    } while (0)

__global__ __launch_bounds__(512, 2) void gemm_bt(const u16* __restrict__ A,
                                                  const u16* __restrict__ B,
                                                  const float* __restrict__ bias,
                                                  float* __restrict__ C) {
    __shared__ u16 lds[65536];  // 128 KiB

    const int tid  = threadIdx.x;
    const int lane = tid & 63;
    const int wave = tid >> 6;     // 0..7
    const int wm   = wave >> 2;    // 0..1 (M)
    const int wn   = wave & 3;     // 0..3 (N)
    const int fr   = lane & 15;    // fragment row index
    const int q    = lane >> 4;    // k-quad (8 bf16 = 16B)

    // Bijective XCD-chunked swizzle: 1024 wgs, 8 XCDs, 128 per chunk.
    const int wg  = blockIdx.x;
    const int swz = (wg & 7) * 128 + (wg >> 3);
    const int m0  = (swz >> 4) * 256;
    const int n0  = (swz & 15) * 256;

    // Per-thread LDS read offsets (u16 units), 2-bit XOR swizzle.
    // All fragment rows have row%4 == fr%4, so the XOR key is (fr&3).
    const int ck0 = (((0 * 64) + q * 16) ^ ((fr & 3) << 5)) >> 1;
    const int ck1 = (((1 * 64) + q * 16) ^ ((fr & 3) << 5)) >> 1;
    const int arow = (wm * 64 + fr) * 64;  // + i*1024 + region base
    const int brow = (wn * 32 + fr) * 64;  // + j*1024 + region base

    float4_t acc[2][2][4][2];
    const float4_t fzero = {0.f, 0.f, 0.f, 0.f};
#pragma unroll
    for (int mh = 0; mh < 2; ++mh)
#pragma unroll
        for (int nh = 0; nh < 2; ++nh)
#pragma unroll
            for (int i = 0; i < 4; ++i)
#pragma unroll
                for (int j = 0; j < 2; ++j) acc[mh][nh][i][j] = fzero;

    short8 afr[4][2], bfr0[2][2], bfr1[2][2];

    // ---- prologue: buf0 <- tile0 (all 4 regions); buf1.B <- tile1 in flight ----
    stage_half(A, m0 + 0,   0, lds + 0,     wave, lane);  // buf0.A.h0
    stage_half(A, m0 + 128, 0, lds + 8192,  wave, lane);  // buf0.A.h1
    stage_half(B, n0 + 0,   0, lds + 16384, wave, lane);  // buf0.B.h0
    stage_half(B, n0 + 128, 0, lds + 24576, wave, lane);  // buf0.B.h1
    stage_half(B, n0 + 0,   1, lds + 49152, wave, lane);  // buf1.B.h0 (t1)
    stage_half(B, n0 + 128, 1, lds + 57344, wave, lane);  // buf1.B.h1 (t1)
    asm volatile("s_waitcnt vmcnt(4)" ::: "memory");      // buf0 landed
    __builtin_amdgcn_s_barrier();

    // ---- main loop: 8 iterations, 2 K-tiles each ----
    // Read schedule per buffer (zigzag): P_a(0,0): A.h0+B.h0; P_b(1,0): A.h1
    // (reuse bfr0); P_c(1,1): B.h1 (reuse afr); P_d(0,1): A.h0 again (reuse
    // bfr1). Region free-after / staged-at (all land under vmcnt(4)@P4/P8,
    // which drains everything issued >= 4 stage-halfs ago):
    //   buf1.A.h0: read P5,P8 -> staged P1 (t1, read this iter P5)
    //   buf1.A.h1: read P6    -> staged P2 (t1)
    //   buf0.B.h0: read P1    -> staged P3 (t2)
    //   buf0.B.h1: read P3    -> staged P4 (t2)
    //   buf0.A.h0: read P1,P4 -> staged P5 (t2)
    //   buf0.A.h1: read P2    -> staged P6 (t2)
    //   buf1.B.h0: read P5    -> staged P7 (t3)
    //   buf1.B.h1: read P7    -> staged P8 (t3)
    // vmcnt(4)@P4: drains prev-P7/P8 (buf1.B t1) + P1/P2 (buf1.A t1) -> buf1
    // complete before P5. vmcnt(4)@P8: drains P3..P6 -> buf0(t2) complete
    // before next P1.
    for (int it = 0; it < NT / 2; ++it) {
        const int u  = 2 * it;
        const int t1 = u + 1;
        const int t2 = (u + 2 < NT) ? u + 2 : NT - 1;  // tail clamp (unread)
        const int t3 = (u + 3 < NT) ? u + 3 : NT - 1;

        // P1: buf0 (0,0)
        LOAD_AFR(0); LOAD_BFR(16384, bfr0);
        stage_half(A, m0 + 0, t1, lds + 32768, wave, lane);
        MFMA16(0, 0, bfr0);
        __builtin_amdgcn_s_barrier();

        // P2: buf0 (1,0) — reuse bfr0
        LOAD_AFR(8192);
        stage_half(A, m0 + 128, t1, lds + 40960, wave, lane);
        MFMA16(1, 0, bfr0);
        __builtin_amdgcn_s_barrier();

        // P3: buf0 (1,1) — reuse afr(h1)
        LOAD_BFR(24576, bfr1);
        stage_half(B, n0 + 0, t2, lds + 16384, wave, lane);
        MFMA16(1, 1, bfr1);
        __builtin_amdgcn_s_barrier();

        // P4: buf0 (0,1) — re-read A.h0, reuse bfr1; tile t1 must land
        LOAD_AFR(0);
        stage_half(B, n0 + 128, t2, lds + 24576, wave, lane);
        MFMA16(0, 1, bfr1);
        asm volatile("s_waitcnt vmcnt(4)" ::: "memory");
        __builtin_amdgcn_s_barrier();

        // P5: buf1 (0,0)
        LOAD_AFR(32768); LOAD_BFR(49152, bfr0);
        stage_half(A, m0 + 0, t2, lds + 0, wave, lane);
        MFMA16(0, 0, bfr0);
        __builtin_amdgcn_s_barrier();

        // P6: buf1 (1,0) — reuse bfr0
        LOAD_AFR(40960);
        stage_half(A, m0 + 128, t2, lds + 8192, wave, lane);
        MFMA16(1, 0, bfr0);
        __builtin_amdgcn_s_barrier();

        // P7: buf1 (1,1) — reuse afr(h1)
        LOAD_BFR(57344, bfr1);
        stage_half(B, n0 + 0, t3, lds + 49152, wave, lane);
        MFMA16(1, 1, bfr1);
        __builtin_amdgcn_s_barrier();

        // P8: buf1 (0,1) — re-read A.h0, reuse bfr1; tile t2 must land
        LOAD_AFR(32768);
        stage_half(B, n0 + 128, t3, lds + 57344, wave, lane);
        MFMA16(0, 1, bfr1);
        asm volatile("s_waitcnt vmcnt(4)" ::: "memory");
        __builtin_amdgcn_s_barrier();
    }

    // Drain outstanding LDS-DMA before block exit (next block reuses LDS).
    asm volatile("s_waitcnt vmcnt(0)" ::: "memory");
    __builtin_amdgcn_s_barrier();

    // ---- epilogue: D mapping col = lane&15, row = (lane>>4)*4 + reg ----
    const int rq = (lane >> 4) * 4;
#pragma unroll
    for (int nh = 0; nh < 2; ++nh) {
#pragma unroll
        for (int j = 0; j < 2; ++j) {
            const int col  = n0 + nh * 128 + wn * 32 + j * 16 + fr;
            const float bj = bias[col];
#pragma unroll
            for (int mh = 0; mh < 2; ++mh) {
#pragma unroll
                for (int i = 0; i < 4; ++i) {
                    const int row = m0 + mh * 128 + wm * 64 + i * 16 + rq;
#pragma unroll
                    for (int r = 0; r < 4; ++r) {
                        C[(size_t)(row + r) * N_TOT + col] = acc[mh][nh][i][j][r] + bj;
                    }
                }
            }
        }
    }
}

// ---- fallback (only if ws too small): slow but correct, pure fp32 ----
__global__ __launch_bounds__(256) void fallback_k(const float* __restrict__ X,
                                                  const float* __restrict__ W,
                                                  const float* __restrict__ bias,
                                                  float* __restrict__ out) {
    size_t idx = (size_t)blockIdx.x * 256 + threadIdx.x;
    int n    = (int)(idx & (N_TOT - 1));
    size_t m = idx >> 12;
    const float* xr = X + m * K_ACT;
    const float* wr = W + (size_t)n * K_ACT;
    float acc = 0.f;
    for (int g = 0; g < K_ACT / 8; ++g) {
        acc += xr[g * 8] * wr[g * 8] + xr[g * 8 + 2] * wr[g * 8 + 2];
    }
    out[idx] = acc + bias[n];
}

extern "C" void kernel_launch(void* const* d_in, const int* in_sizes, int n_in,
                              void* d_out, int out_size, void* d_ws, size_t ws_size,
                              hipStream_t stream) {
    const float* x    = (const float*)d_in[0];   // [16384, 4096] fp32
    const float* w    = (const float*)d_in[1];   // [4096, 4096] fp32
    const float* bias = (const float*)d_in[2];   // [4096] fp32
    float* out = (float*)d_out;                  // [16384, 4096] fp32

    const size_t xc_elems = (size_t)M_TOT * K_C;             // 16M u16 = 33.5 MB
    const size_t wc_elems = (size_t)N_TOT * K_C;             //  4M u16 =  8.4 MB
    const size_t need = (xc_elems + wc_elems) * sizeof(u16);

    if (ws_size >= need) {
        u16* xc = (u16*)d_ws;
        u16* wc = xc + xc_elems;

        const int ngx = M_TOT * (K_ACT / 8);                 // 8,388,608 groups
        const int ngw = N_TOT * (K_ACT / 8);                 // 2,097,152 groups
        compact_k<<<ngx / 256, 256, 0, stream>>>((const float4*)x, (u32*)xc, ngx);
        compact_k<<<ngw / 256, 256, 0, stream>>>((const float4*)w, (u32*)wc, ngw);

        gemm_bt<<<dim3(1024), dim3(512), 0, stream>>>(xc, wc, bias, out);
    } else {
        const size_t total = (size_t)M_TOT * N_TOT;
        fallback_k<<<(int)(total / 256), 256, 0, stream>>>(x, w, bias, out);
    }
}